// Round 2
// baseline (43625.150 us; speedup 1.0000x reference)
//
#include <hip/hip_runtime.h>
#include <math.h>

typedef __bf16 bf16x8 __attribute__((ext_vector_type(8)));
typedef float f32x4 __attribute__((ext_vector_type(4)));
typedef unsigned short u16;
typedef unsigned int u32;

#define MFMA16(a, b, c) __builtin_amdgcn_mfma_f32_16x16x32_bf16((a), (b), (c), 0, 0, 0)

namespace {
constexpr int kB = 32, kS = 2048, kI = 128, kH = 512, kO = 128;
constexpr int NC = 2;      // independent batch clusters of 16
constexpr int BPC = 16;    // batches per cluster (== MFMA M)
constexpr int L0WG = 16;   // layer-0 WGs per cluster (32 cols each)
constexpr int WGC = 48;    // + 32 layer-1 WGs (16 cols each)
constexpr int NT = 2 * kS + 3;  // 2 ticks/step (A: z,r,rh ; B: g,update) + pipeline tail
constexpr long LOUT = (long)kB * kS * kO;

// workspace byte offsets
constexpr size_t WS_CTR  = 0;
constexpr size_t WS_PUB0 = 512;                                        // h0  [NC][2][16][512] bf16
constexpr size_t WS_PUB1 = WS_PUB0 + (size_t)NC * 2 * BPC * kH * 2;    // h1
constexpr size_t WS_PR0  = WS_PUB1 + (size_t)NC * 2 * BPC * kH * 2;    // rh0
constexpr size_t WS_PR1  = WS_PR0  + (size_t)NC * 2 * BPC * kH * 2;    // rh1
constexpr size_t WS_WTS  = WS_PR1  + (size_t)NC * 2 * BPC * kH * 2;

// weight element offsets (u16) within WS_WTS
constexpr int W0H = 0;        // [3][512][512]  (z,r,g)
constexpr int W0X = 786432;   // [3][512][128]
constexpr int W1X = 983040;   // [3][512][512]
constexpr int W1H = 1769472;  // [3][512][512]
constexpr int WYO = 2555904;  // [128][512]

constexpr int HP = 520;  // padded LDS row stride (u16), K=512 rows
constexpr int IP = 136;  // padded LDS row stride (u16), K=128 rows
}

__device__ __forceinline__ u16 f2bf(float f) {
  u32 x = __float_as_uint(f);
  return (u16)((x + 0x7fffu + ((x >> 16) & 1u)) >> 16);  // RNE
}

// ---------------- prep: fp32 -> bf16 weights, init publish bufs & counters ----
__global__ void prep_kernel(const float* whz0, const float* whr0, const float* whg0,
                            const float* wxz0, const float* wxr0, const float* wxg0,
                            const float* wxz1, const float* wxr1, const float* wxg1,
                            const float* whz1, const float* whr1, const float* whg1,
                            const float* wy, const float* h0in, char* ws) {
  u16* wts = (u16*)(ws + WS_WTS);
  int gid = blockIdx.x * blockDim.x + threadIdx.x;
  int stride = gridDim.x * blockDim.x;
  for (int i = gid; i < 786432; i += stride) {
    int g = i >> 18, r = i & 262143;
    wts[W0H + i] = f2bf((g == 0 ? whz0 : g == 1 ? whr0 : whg0)[r]);
  }
  for (int i = gid; i < 196608; i += stride) {
    int g = i >> 16, r = i & 65535;
    wts[W0X + i] = f2bf((g == 0 ? wxz0 : g == 1 ? wxr0 : wxg0)[r]);
  }
  for (int i = gid; i < 786432; i += stride) {
    int g = i >> 18, r = i & 262143;
    wts[W1X + i] = f2bf((g == 0 ? wxz1 : g == 1 ? wxr1 : wxg1)[r]);
  }
  for (int i = gid; i < 786432; i += stride) {
    int g = i >> 18, r = i & 262143;
    wts[W1H + i] = f2bf((g == 0 ? whz1 : g == 1 ? whr1 : whg1)[r]);
  }
  for (int i = gid; i < 65536; i += stride) wts[WYO + i] = f2bf(wy[i]);

  u16* p0 = (u16*)(ws + WS_PUB0);
  u16* p1 = (u16*)(ws + WS_PUB1);
  for (int i = gid; i < NC * BPC * kH; i += stride) {
    int c = i / (BPC * kH), rem = i - c * (BPC * kH);
    int b = rem / kH, k = rem - b * kH;
    int bg = c * BPC + b;
    p0[(c * 2 + 1) * BPC * kH + rem] = f2bf(h0in[(size_t)bg * 2 * kH + k]);
    p1[(c * 2 + 1) * BPC * kH + rem] = f2bf(h0in[(size_t)bg * 2 * kH + kH + k]);
  }
  if (gid < NC) *(u32*)(ws + WS_CTR + (size_t)gid * 256) = 0u;
}

// ---------------- helpers ----------------
__device__ __forceinline__ void stage_h(u16* dst, const u16* src) {
  // copy [16][512] u16 -> LDS [16][HP], 256 threads x 4 x 16B
  int t = threadIdx.x;
#pragma unroll
  for (int j = 0; j < 4; ++j) {
    int ch = t + j * 256;
    int b = ch >> 6, i = (ch & 63) * 8;
    *(int4*)(dst + b * HP + i) = *(const int4*)(src + b * kH + i);
  }
}

__device__ __forceinline__ void st_tile(float* base, f32x4 c, int q, int li) {
  // C/D layout: D[row=q*4+r][col=li]; row = batch. Stride 17 spreads banks.
#pragma unroll
  for (int r = 0; r < 4; ++r) base[(q * 4 + r) * 17 + li] = c[r];
}

__device__ __forceinline__ float sigm(float x) { return 1.f / (1.f + __expf(-x)); }
__device__ __forceinline__ float tanh_f(float x) {
  float te = __expf(-2.f * fabsf(x));
  return __builtin_copysignf((1.f - te) / (1.f + te), x);
}

__device__ __forceinline__ void cbar(u32* ctr, u32 target) {
  __syncthreads();                 // drains this WG's stores (vmcnt 0)
  if (threadIdx.x == 0) {
    __threadfence();               // device-scope release
    atomicAdd(ctr, 1u);
    while (__hip_atomic_load(ctr, __ATOMIC_RELAXED, __HIP_MEMORY_SCOPE_AGENT) < target)
      __builtin_amdgcn_s_sleep(1);
  }
  __syncthreads();
  __threadfence();                 // device-scope acquire
}

// ---------------- persistent pipelined GRU ----------------
__global__ __launch_bounds__(256, 1)
void gru_kernel(const float* __restrict__ xg, const float* __restrict__ h0in,
                const float* __restrict__ bxz0, const float* __restrict__ bxr0,
                const float* __restrict__ bxg0, const float* __restrict__ bxz1,
                const float* __restrict__ bxr1, const float* __restrict__ bxg1,
                const float* __restrict__ byv, float* __restrict__ out, char* ws) {
  const int cl = blockIdx.x / WGC;
  const int wid = blockIdx.x - cl * WGC;
  const bool isL0 = wid < L0WG;
  const int w0 = wid, w1 = wid - L0WG;
  const int tid = threadIdx.x;
  const int lane = tid & 63, wv = tid >> 6;
  const int q = lane >> 4, li = lane & 15;
  const int kh = wv & 1;   // K-half this wave owns
  const int nt = wv >> 1;  // L0: which 16-col tile of the WG's 32 cols
  const bool xside = wv < 2;  // L1 role split

  u16* pub0 = (u16*)(ws + WS_PUB0) + (size_t)cl * 2 * BPC * kH;
  u16* pub1 = (u16*)(ws + WS_PUB1) + (size_t)cl * 2 * BPC * kH;
  u16* pr0  = (u16*)(ws + WS_PR0)  + (size_t)cl * 2 * BPC * kH;
  u16* pr1  = (u16*)(ws + WS_PR1)  + (size_t)cl * 2 * BPC * kH;
  const u16* wts = (const u16*)(ws + WS_WTS);
  u32* ctr = (u32*)(ws + WS_CTR + (size_t)cl * 256);

  __shared__ __align__(16) char smem[63360];
  u16* h0buf = (u16*)smem;              // even ticks; odd: rhbuf alias
  u16* h1buf = (u16*)(smem + 16640);    // L1 even
  u16* xbuf  = (u16*)(smem + 16640);    // L0 even (alias h1buf)
  u16* rhbuf = (u16*)smem;              // odd ticks
  float* spA = (float*)(smem + 33280);  // even: L0 5 kinds x2nt x2kh x272 ; L1 5 kinds x2kh
  float* spB = (float*)(smem + 33280);  // odd: g partials
  float* hm  = (float*)(smem + 55040);  // f32 master state slice
  float* zst = (float*)(smem + 57088);  // stash z (phase A -> B)
  float* xgst= (float*)(smem + 59136);  // stash xg pre-act + bias
  float* ypA = (float*)(smem + 61184);  // y partials [2kh][272]

  // ---- persistent register-resident weight fragments ----
  // B-frag: lane holds W[col=li-slice][k = kh*256 + s*32 + q*8 .. +7]
  bf16x8 wA[3][8];  // L0: Wh0 z/r/g | L1 x-waves: W1x z/r/g | L1 h-waves: W1h z/r/g
  bf16x8 wE[8];     // L0: Wx0 z/r/g packed [g*2+s] | L1 h-waves w1<8: wy
  if (isL0) {
    const int ci = w0 * 32 + nt * 16 + li;
#pragma unroll
    for (int g = 0; g < 3; ++g)
#pragma unroll
      for (int s = 0; s < 8; ++s)
        wA[g][s] = *(const bf16x8*)(wts + W0H + ((size_t)(g * kH + ci) * kH + kh * 256 + q * 8 + s * 32));
#pragma unroll
    for (int g = 0; g < 3; ++g)
#pragma unroll
      for (int s = 0; s < 2; ++s)
        wE[g * 2 + s] = *(const bf16x8*)(wts + W0X + ((size_t)(g * kH + ci) * kI + kh * 64 + q * 8 + s * 32));
  } else {
    const int ci = w1 * 16 + li;
    const int base = xside ? W1X : W1H;
#pragma unroll
    for (int g = 0; g < 3; ++g)
#pragma unroll
      for (int s = 0; s < 8; ++s)
        wA[g][s] = *(const bf16x8*)(wts + base + ((size_t)(g * kH + ci) * kH + kh * 256 + q * 8 + s * 32));
    if (!xside && w1 < 8) {
#pragma unroll
      for (int s = 0; s < 8; ++s)
        wE[s] = *(const bf16x8*)(wts + WYO + ((size_t)ci * kH + kh * 256 + q * 8 + s * 32));
    }
  }

  // ---- biases (regs) + f32 master state (LDS) init ----
  float bz_r = 0.f, br_r = 0.f, bg_r = 0.f, by_r = 0.f;
  if (isL0) {
    int c = tid & 31, b0 = tid >> 5;
    bz_r = bxz0[w0 * 32 + c];
    br_r = bxr0[w0 * 32 + c];
    bg_r = bxg0[w0 * 32 + c];
    hm[b0 * 32 + c] = h0in[(size_t)(cl * 16 + b0) * 2 * kH + w0 * 32 + c];
    hm[(b0 + 8) * 32 + c] = h0in[(size_t)(cl * 16 + b0 + 8) * 2 * kH + w0 * 32 + c];
  } else {
    int c = tid & 15, b = tid >> 4;
    bz_r = bxz1[w1 * 16 + c];
    br_r = bxr1[w1 * 16 + c];
    bg_r = bxg1[w1 * 16 + c];
    if (w1 < 8) by_r = byv[w1 * 16 + c];
    hm[b * 16 + c] = h0in[(size_t)(cl * 16 + b) * 2 * kH + kH + w1 * 16 + c];
  }
  __syncthreads();

  for (int tk = 0; tk < NT; ++tk) {
    const bool ev = (tk & 1) == 0;
    const int t = tk >> 1;          // L0 step (phase A at 2t, B at 2t+1)
    const int u = t - 1;            // L1 step
    const bool l0A = isL0 && ev && t < kS;
    const bool l0B = isL0 && !ev && t < kS;
    const bool l1A = !isL0 && ev && t >= 1 && t <= kS;
    const bool l1B = !isL0 && !ev && t >= 1 && t <= kS;
    const bool stH1 = !isL0 && ev && t >= 1 && t <= kS + 1;
    const bool yAct = !isL0 && ev && w1 < 8 && t >= 2 && t <= kS + 1;

    // ---- stage ----
    if (l0A) {
      stage_h(h0buf, pub0 + ((t - 1) & 1) * BPC * kH);
      int b = tid >> 4, i0 = (tid & 15) * 8;
      const float* xr = xg + ((size_t)(cl * 16 + b) * kS + t) * kI + i0;
      float4 v0 = *(const float4*)xr;
      float4 v1 = *(const float4*)(xr + 4);
      int4 pk;
      pk.x = (int)((u32)f2bf(v0.x) | ((u32)f2bf(v0.y) << 16));
      pk.y = (int)((u32)f2bf(v0.z) | ((u32)f2bf(v0.w) << 16));
      pk.z = (int)((u32)f2bf(v1.x) | ((u32)f2bf(v1.y) << 16));
      pk.w = (int)((u32)f2bf(v1.z) | ((u32)f2bf(v1.w) << 16));
      *(int4*)(xbuf + b * IP + i0) = pk;
    }
    if (l1A) stage_h(h0buf, pub0 + (u & 1) * BPC * kH);
    if (stH1) stage_h(h1buf, pub1 + ((u - 1) & 1) * BPC * kH);
    if (l0B) stage_h(rhbuf, pr0 + (t & 1) * BPC * kH);
    if (l1B) stage_h(rhbuf, pr1 + (u & 1) * BPC * kH);
    __syncthreads();

    // ---- MFMA (A-frag: lane holds A[m=li][k=kh*256+s*32+q*8..+7]) ----
    if (l0A) {
      f32x4 hz = {0.f, 0.f, 0.f, 0.f}, hr = hz, xz = hz, xr2 = hz, xg2 = hz;
      const u16* ap = h0buf + li * HP + kh * 256 + q * 8;
#pragma unroll
      for (int s = 0; s < 8; ++s) {
        bf16x8 a = *(const bf16x8*)(ap + s * 32);
        hz = MFMA16(a, wA[0][s], hz);
        hr = MFMA16(a, wA[1][s], hr);
      }
      const u16* xp = xbuf + li * IP + kh * 64 + q * 8;
#pragma unroll
      for (int s = 0; s < 2; ++s) {
        bf16x8 a = *(const bf16x8*)(xp + s * 32);
        xz  = MFMA16(a, wE[0 + s], xz);
        xr2 = MFMA16(a, wE[2 + s], xr2);
        xg2 = MFMA16(a, wE[4 + s], xg2);
      }
      st_tile(spA + ((0 * 2 + nt) * 2 + kh) * 272, hz, q, li);
      st_tile(spA + ((1 * 2 + nt) * 2 + kh) * 272, hr, q, li);
      st_tile(spA + ((2 * 2 + nt) * 2 + kh) * 272, xz, q, li);
      st_tile(spA + ((3 * 2 + nt) * 2 + kh) * 272, xr2, q, li);
      st_tile(spA + ((4 * 2 + nt) * 2 + kh) * 272, xg2, q, li);
    } else if (!isL0 && ev) {
      if (xside) {
        if (l1A) {  // x-side of layer 1: input is h0(u)
          f32x4 cz = {0.f, 0.f, 0.f, 0.f}, cr = cz, cg = cz;
          const u16* ap = h0buf + li * HP + kh * 256 + q * 8;
#pragma unroll
          for (int s = 0; s < 8; ++s) {
            bf16x8 a = *(const bf16x8*)(ap + s * 32);
            cz = MFMA16(a, wA[0][s], cz);
            cr = MFMA16(a, wA[1][s], cr);
            cg = MFMA16(a, wA[2][s], cg);
          }
          st_tile(spA + (2 * 2 + kh) * 272, cz, q, li);
          st_tile(spA + (3 * 2 + kh) * 272, cr, q, li);
          st_tile(spA + (4 * 2 + kh) * 272, cg, q, li);
        }
      } else {
        const bool rec = t >= 1 && t <= kS;
        const bool ym = (w1 < 8) && t >= 2 && t <= kS + 1;
        if (rec || ym) {  // h-side z,r of layer 1 + y, both consume h1buf
          f32x4 cz = {0.f, 0.f, 0.f, 0.f}, cr = cz, cy = cz;
          const u16* ap = h1buf + li * HP + kh * 256 + q * 8;
#pragma unroll
          for (int s = 0; s < 8; ++s) {
            bf16x8 a = *(const bf16x8*)(ap + s * 32);
            if (rec) {
              cz = MFMA16(a, wA[0][s], cz);
              cr = MFMA16(a, wA[1][s], cr);
            }
            if (ym) cy = MFMA16(a, wE[s], cy);
          }
          if (rec) {
            st_tile(spA + (0 * 2 + kh) * 272, cz, q, li);
            st_tile(spA + (1 * 2 + kh) * 272, cr, q, li);
          }
          if (ym) st_tile(ypA + kh * 272, cy, q, li);
        }
      }
    } else if (l0B) {
      f32x4 cg = {0.f, 0.f, 0.f, 0.f};
      const u16* ap = rhbuf + li * HP + kh * 256 + q * 8;
#pragma unroll
      for (int s = 0; s < 8; ++s)
        cg = MFMA16(*(const bf16x8*)(ap + s * 32), wA[2][s], cg);
      st_tile(spB + (nt * 2 + kh) * 272, cg, q, li);
    } else if (l1B && !xside) {
      f32x4 cg = {0.f, 0.f, 0.f, 0.f};
      const u16* ap = rhbuf + li * HP + kh * 256 + q * 8;
#pragma unroll
      for (int s = 0; s < 8; ++s)
        cg = MFMA16(*(const bf16x8*)(ap + s * 32), wA[2][s], cg);
      st_tile(spB + kh * 272, cg, q, li);
    }
    __syncthreads();

    // ---- activations / publish ----
    if (l0A) {
      const int c = tid & 31, b0 = tid >> 5;
      const int n2 = c >> 4, cc = c & 15;
#pragma unroll
      for (int r2 = 0; r2 < 2; ++r2) {
        int b = b0 + r2 * 8;
        int o = b * 17 + cc;
        float hz = spA[((0 * 2 + n2) * 2 + 0) * 272 + o] + spA[((0 * 2 + n2) * 2 + 1) * 272 + o];
        float hr = spA[((1 * 2 + n2) * 2 + 0) * 272 + o] + spA[((1 * 2 + n2) * 2 + 1) * 272 + o];
        float xz = spA[((2 * 2 + n2) * 2 + 0) * 272 + o] + spA[((2 * 2 + n2) * 2 + 1) * 272 + o];
        float xr = spA[((3 * 2 + n2) * 2 + 0) * 272 + o] + spA[((3 * 2 + n2) * 2 + 1) * 272 + o];
        float xgv= spA[((4 * 2 + n2) * 2 + 0) * 272 + o] + spA[((4 * 2 + n2) * 2 + 1) * 272 + o];
        float z = sigm(hz + xz + bz_r);
        float r = sigm(hr + xr + br_r);
        zst[b * 32 + c] = z;
        xgst[b * 32 + c] = xgv + bg_r;
        float rh = r * hm[b * 32 + c];
        pr0[(t & 1) * BPC * kH + b * kH + w0 * 32 + c] = f2bf(rh);
      }
    }
    if (l1A) {
      const int c = tid & 15, b = tid >> 4;
      const int o = b * 17 + c;
      float hz = spA[(0 * 2 + 0) * 272 + o] + spA[(0 * 2 + 1) * 272 + o];
      float hr = spA[(1 * 2 + 0) * 272 + o] + spA[(1 * 2 + 1) * 272 + o];
      float xz = spA[(2 * 2 + 0) * 272 + o] + spA[(2 * 2 + 1) * 272 + o];
      float xr = spA[(3 * 2 + 0) * 272 + o] + spA[(3 * 2 + 1) * 272 + o];
      float xgv= spA[(4 * 2 + 0) * 272 + o] + spA[(4 * 2 + 1) * 272 + o];
      float z = sigm(hz + xz + bz_r);
      float r = sigm(hr + xr + br_r);
      zst[b * 16 + c] = z;
      xgst[b * 16 + c] = xgv + bg_r;
      float rh = r * hm[b * 16 + c];
      pr1[(u & 1) * BPC * kH + b * kH + w1 * 16 + c] = f2bf(rh);
    }
    if (yAct) {
      const int c = tid & 15, b = tid >> 4;
      float y = ypA[b * 17 + c] + ypA[272 + b * 17 + c] + by_r;
      out[((size_t)(cl * 16 + b) * kS + (t - 2)) * kO + w1 * 16 + c] = y;
    }
    if (l0B) {
      const int c = tid & 31, b0 = tid >> 5;
      const int n2 = c >> 4, cc = c & 15;
#pragma unroll
      for (int r2 = 0; r2 < 2; ++r2) {
        int b = b0 + r2 * 8;
        int o = b * 17 + cc;
        float gh = spB[(n2 * 2 + 0) * 272 + o] + spB[(n2 * 2 + 1) * 272 + o];
        float g = tanh_f(xgst[b * 32 + c] + gh);
        float z = zst[b * 32 + c];
        float hp = hm[b * 32 + c];
        float hn = z * hp + (1.f - z) * g;
        hm[b * 32 + c] = hn;
        pub0[(t & 1) * BPC * kH + b * kH + w0 * 32 + c] = f2bf(hn);
        if (t == kS - 1) out[LOUT + (size_t)(cl * 16 + b) * 2 * kH + w0 * 32 + c] = hn;
      }
    }
    if (l1B) {
      const int c = tid & 15, b = tid >> 4;
      const int o = b * 17 + c;
      float gh = spB[0 * 272 + o] + spB[1 * 272 + o];
      float g = tanh_f(xgst[b * 16 + c] + gh);
      float z = zst[b * 16 + c];
      float hp = hm[b * 16 + c];
      float hn = z * hp + (1.f - z) * g;
      hm[b * 16 + c] = hn;
      pub1[(u & 1) * BPC * kH + b * kH + w1 * 16 + c] = f2bf(hn);
      if (u == kS - 1) out[LOUT + (size_t)(cl * 16 + b) * 2 * kH + kH + w1 * 16 + c] = hn;
    }

    if (tk != NT - 1) cbar(ctr, (u32)(WGC * (tk + 1)));
  }
}

extern "C" void kernel_launch(void* const* d_in, const int* in_sizes, int n_in,
                              void* d_out, int out_size, void* d_ws, size_t ws_size,
                              hipStream_t stream) {
  (void)in_sizes; (void)n_in; (void)out_size; (void)ws_size;
  const float* x      = (const float*)d_in[0];
  const float* h0     = (const float*)d_in[1];
  const float* l0_wxz = (const float*)d_in[2];
  const float* l0_bxz = (const float*)d_in[3];
  const float* l0_whz = (const float*)d_in[4];
  const float* l0_wxr = (const float*)d_in[5];
  const float* l0_bxr = (const float*)d_in[6];
  const float* l0_whr = (const float*)d_in[7];
  const float* l0_wxg = (const float*)d_in[8];
  const float* l0_bxg = (const float*)d_in[9];
  const float* l0_whg = (const float*)d_in[10];
  const float* l1_wxz = (const float*)d_in[11];
  const float* l1_bxz = (const float*)d_in[12];
  const float* l1_whz = (const float*)d_in[13];
  const float* l1_wxr = (const float*)d_in[14];
  const float* l1_bxr = (const float*)d_in[15];
  const float* l1_whr = (const float*)d_in[16];
  const float* l1_wxg = (const float*)d_in[17];
  const float* l1_bxg = (const float*)d_in[18];
  const float* l1_whg = (const float*)d_in[19];
  const float* wy     = (const float*)d_in[20];
  const float* by     = (const float*)d_in[21];
  float* out = (float*)d_out;
  char* ws = (char*)d_ws;

  prep_kernel<<<512, 256, 0, stream>>>(l0_whz, l0_whr, l0_whg, l0_wxz, l0_wxr, l0_wxg,
                                       l1_wxz, l1_wxr, l1_wxg, l1_whz, l1_whr, l1_whg,
                                       wy, h0, ws);
  gru_kernel<<<NC * WGC, 256, 0, stream>>>(x, h0, l0_bxz, l0_bxr, l0_bxg,
                                           l1_bxz, l1_bxr, l1_bxg, by, out, ws);
}

// Round 3
// 19618.759 us; speedup vs baseline: 2.2236x; 2.2236x over previous
//
#include <hip/hip_runtime.h>
#include <math.h>

typedef __bf16 bf16x8 __attribute__((ext_vector_type(8)));
typedef float f32x4 __attribute__((ext_vector_type(4)));
typedef unsigned short u16;
typedef unsigned int u32;
typedef unsigned long long u64;

#define MFMA16(a, b, c) __builtin_amdgcn_mfma_f32_16x16x32_bf16((a), (b), (c), 0, 0, 0)

namespace {
constexpr int kB = 32, kS = 2048, kI = 128, kH = 512, kO = 128;
constexpr int NC = 2;      // independent batch clusters of 16
constexpr int BPC = 16;    // batches per cluster (== MFMA M)
constexpr int L0WG = 16;   // layer-0 WGs per cluster (32 cols each)
constexpr int WGC = 48;    // + 32 layer-1 WGs (16 cols each)
constexpr int NT = 2 * kS + 3;  // 2 ticks/step (A: z,r,rh ; B: g,update) + tail
constexpr long LOUT = (long)kB * kS * kO;

// workspace byte offsets
constexpr size_t WS_FLG  = 0;                                          // [NC][48] flags, 64B stride
constexpr size_t WS_PUB0 = 8192;                                       // h0  [NC][2][16][512] bf16
constexpr size_t WS_PUB1 = WS_PUB0 + (size_t)NC * 2 * BPC * kH * 2;
constexpr size_t WS_PR0  = WS_PUB1 + (size_t)NC * 2 * BPC * kH * 2;    // rh0
constexpr size_t WS_PR1  = WS_PR0  + (size_t)NC * 2 * BPC * kH * 2;    // rh1
constexpr size_t WS_WTS  = WS_PR1  + (size_t)NC * 2 * BPC * kH * 2;

// weight element offsets (u16) within WS_WTS
constexpr int W0H = 0;        // [3][512][512]  (z,r,g)
constexpr int W0X = 786432;   // [3][512][128]
constexpr int W1X = 983040;   // [3][512][512]
constexpr int W1H = 1769472;  // [3][512][512]
constexpr int WYO = 2555904;  // [128][512]

constexpr int HP = 520;  // padded LDS row stride (u16), K=512 rows
constexpr int IP = 136;  // padded LDS row stride (u16), K=128 rows
}

__device__ __forceinline__ u16 f2bf(float f) {
  u32 x = __float_as_uint(f);
  return (u16)((x + 0x7fffu + ((x >> 16) & 1u)) >> 16);  // RNE
}

// ---------------- prep: fp32 -> bf16 weights, init publish bufs & flags ----
__global__ void prep_kernel(const float* whz0, const float* whr0, const float* whg0,
                            const float* wxz0, const float* wxr0, const float* wxg0,
                            const float* wxz1, const float* wxr1, const float* wxg1,
                            const float* whz1, const float* whr1, const float* whg1,
                            const float* wy, const float* h0in, char* ws) {
  u16* wts = (u16*)(ws + WS_WTS);
  int gid = blockIdx.x * blockDim.x + threadIdx.x;
  int stride = gridDim.x * blockDim.x;
  for (int i = gid; i < 786432; i += stride) {
    int g = i >> 18, r = i & 262143;
    wts[W0H + i] = f2bf((g == 0 ? whz0 : g == 1 ? whr0 : whg0)[r]);
  }
  for (int i = gid; i < 196608; i += stride) {
    int g = i >> 16, r = i & 65535;
    wts[W0X + i] = f2bf((g == 0 ? wxz0 : g == 1 ? wxr0 : wxg0)[r]);
  }
  for (int i = gid; i < 786432; i += stride) {
    int g = i >> 18, r = i & 262143;
    wts[W1X + i] = f2bf((g == 0 ? wxz1 : g == 1 ? wxr1 : wxg1)[r]);
  }
  for (int i = gid; i < 786432; i += stride) {
    int g = i >> 18, r = i & 262143;
    wts[W1H + i] = f2bf((g == 0 ? whz1 : g == 1 ? whr1 : whg1)[r]);
  }
  for (int i = gid; i < 65536; i += stride) wts[WYO + i] = f2bf(wy[i]);

  u16* p0 = (u16*)(ws + WS_PUB0);
  u16* p1 = (u16*)(ws + WS_PUB1);
  for (int i = gid; i < NC * BPC * kH; i += stride) {
    int c = i / (BPC * kH), rem = i - c * (BPC * kH);
    int b = rem / kH, k = rem - b * kH;
    int bg = c * BPC + b;
    p0[(c * 2 + 1) * BPC * kH + rem] = f2bf(h0in[(size_t)bg * 2 * kH + k]);
    p1[(c * 2 + 1) * BPC * kH + rem] = f2bf(h0in[(size_t)bg * 2 * kH + kH + k]);
  }
  if (gid < 2048) ((u32*)(ws + WS_FLG))[gid] = 0u;  // barrier flags
}

// ---------------- helpers ----------------
// coherent 16KB stage: [16][512] u16 (IC-coherent) -> LDS [16][HP]
__device__ __forceinline__ void stage_c(u16* dst, const u16* src) {
  u64* s = (u64*)src;
  int t = threadIdx.x;
#pragma unroll
  for (int j = 0; j < 8; ++j) {
    int idx = j * 256 + t;
    u64 v = __hip_atomic_load(s + idx, __ATOMIC_RELAXED, __HIP_MEMORY_SCOPE_AGENT);
    int b = idx >> 7, i = idx & 127;
    *(u64*)(dst + b * HP + i * 4) = v;
  }
}
// same, by half a WG (128 threads, lt in [0,128))
__device__ __forceinline__ void stage_c_half(u16* dst, const u16* src, int lt) {
  u64* s = (u64*)src;
#pragma unroll
  for (int j = 0; j < 16; ++j) {
    int idx = j * 128 + lt;
    u64 v = __hip_atomic_load(s + idx, __ATOMIC_RELAXED, __HIP_MEMORY_SCOPE_AGENT);
    int b = idx >> 7, i = idx & 127;
    *(u64*)(dst + b * HP + i * 4) = v;
  }
}

__device__ __forceinline__ void st_tile(float* base, f32x4 c, int q, int li) {
  // C/D layout: D[row=q*4+r][col=li]; row = batch. Stride 17 spreads banks.
#pragma unroll
  for (int r = 0; r < 4; ++r) base[(q * 4 + r) * 17 + li] = c[r];
}

// publish 2 adjacent bf16 columns as one coherent u32 store
__device__ __forceinline__ void pub2(u16* base, int off, float v0, float v1) {
  u32 pk = (u32)f2bf(v0) | ((u32)f2bf(v1) << 16);
  __hip_atomic_store((u32*)(base + off), pk, __ATOMIC_RELAXED, __HIP_MEMORY_SCOPE_AGENT);
}

__device__ __forceinline__ float sigm(float x) { return 1.f / (1.f + __expf(-x)); }
__device__ __forceinline__ float tanh_f(float x) {
  float te = __expf(-2.f * fabsf(x));
  return __builtin_copysignf((1.f - te) / (1.f + te), x);
}

// flag-array barrier: no fences; publishes are IC-coherent, __syncthreads drains vmcnt
__device__ __forceinline__ void cbar(u32* flags, int wid, u32 target) {
  __syncthreads();  // all waves' coherent stores drained (vmcnt 0) before arrive
  if (threadIdx.x == 0)
    __hip_atomic_store(&flags[wid * 16], target, __ATOMIC_RELAXED, __HIP_MEMORY_SCOPE_AGENT);
  if (threadIdx.x < WGC) {
    while (__hip_atomic_load(&flags[threadIdx.x * 16], __ATOMIC_RELAXED,
                             __HIP_MEMORY_SCOPE_AGENT) < target)
      __builtin_amdgcn_s_sleep(1);
  }
  __syncthreads();
}

// ---------------- persistent pipelined GRU ----------------
__global__ __launch_bounds__(256, 1)
void gru_kernel(const float* __restrict__ xg, const float* __restrict__ h0in,
                const float* __restrict__ bxz0, const float* __restrict__ bxr0,
                const float* __restrict__ bxg0, const float* __restrict__ bxz1,
                const float* __restrict__ bxr1, const float* __restrict__ bxg1,
                const float* __restrict__ byv, float* __restrict__ out, char* ws) {
  const int cl = blockIdx.x / WGC;
  const int wid = blockIdx.x - cl * WGC;
  const bool isL0 = wid < L0WG;
  const int w0 = wid, w1 = wid - L0WG;
  const int tid = threadIdx.x;
  const int lane = tid & 63, wv = tid >> 6;
  const int q = lane >> 4, li = lane & 15;
  const int kh = wv & 1;      // K-half this wave owns
  const int nt = wv >> 1;     // L0: which 16-col tile of the WG's 32 cols
  const bool xside = wv < 2;  // L1 role split

  u16* pub0 = (u16*)(ws + WS_PUB0) + (size_t)cl * 2 * BPC * kH;
  u16* pub1 = (u16*)(ws + WS_PUB1) + (size_t)cl * 2 * BPC * kH;
  u16* pr0  = (u16*)(ws + WS_PR0)  + (size_t)cl * 2 * BPC * kH;
  u16* pr1  = (u16*)(ws + WS_PR1)  + (size_t)cl * 2 * BPC * kH;
  const u16* wts = (const u16*)(ws + WS_WTS);
  u32* flags = (u32*)(ws + WS_FLG) + (size_t)cl * 1024;

  __shared__ __align__(16) char smem[57216];
  u16* h0buf = (u16*)smem;              // even ticks; odd: rhbuf alias
  u16* h1buf = (u16*)(smem + 16640);    // L1 even
  u16* xbuf  = (u16*)(smem + 16640);    // L0 even (alias h1buf)
  u16* rhbuf = (u16*)smem;              // odd ticks
  float* spA = (float*)(smem + 33280);  // even partials; odd: spB alias
  float* spB = (float*)(smem + 33280);
  float* ypA = (float*)(smem + 55040);  // y partials [2kh][272]

  // ---- persistent register-resident weight fragments ----
  // B-frag: lane holds W[col=li-slice][k = kh*256 + s*32 + q*8 .. +7]
  bf16x8 wA[3][8];  // L0: Wh0 z/r/g | L1 x-waves: W1x z/r/g | L1 h-waves: W1h z/r/g
  bf16x8 wE[8];     // L0: Wx0 z/r/g packed [g*2+s] | L1 h-waves w1<8: wy
  if (isL0) {
    const int ci = w0 * 32 + nt * 16 + li;
#pragma unroll
    for (int g = 0; g < 3; ++g)
#pragma unroll
      for (int s = 0; s < 8; ++s)
        wA[g][s] = *(const bf16x8*)(wts + W0H + ((size_t)(g * kH + ci) * kH + kh * 256 + q * 8 + s * 32));
#pragma unroll
    for (int g = 0; g < 3; ++g)
#pragma unroll
      for (int s = 0; s < 2; ++s)
        wE[g * 2 + s] = *(const bf16x8*)(wts + W0X + ((size_t)(g * kH + ci) * kI + kh * 64 + q * 8 + s * 32));
  } else {
    const int ci = w1 * 16 + li;
    const int base = xside ? W1X : W1H;
#pragma unroll
    for (int g = 0; g < 3; ++g)
#pragma unroll
      for (int s = 0; s < 8; ++s)
        wA[g][s] = *(const bf16x8*)(wts + base + ((size_t)(g * kH + ci) * kH + kh * 256 + q * 8 + s * 32));
    if (!xside && w1 < 8) {
#pragma unroll
      for (int s = 0; s < 8; ++s)
        wE[s] = *(const bf16x8*)(wts + WYO + ((size_t)ci * kH + kh * 256 + q * 8 + s * 32));
    }
  }

  // ---- per-thread biases + f32 master state + phase A->B stash (registers) ----
  float2 bz2 = {0.f, 0.f}, br2 = {0.f, 0.f}, bg2 = {0.f, 0.f};
  float by_r = 0.f;
  float hm0r = 0.f, hm1r = 0.f;   // f32 master h for this thread's (b, c0/c1)
  float zA0 = 0.f, zA1 = 0.f, gA0 = 0.f, gA1 = 0.f;  // phase A -> B stash
  if (isL0) {
    const int c0i = (tid & 15) * 2, bq = tid >> 4;
    bz2 = *(const float2*)(bxz0 + w0 * 32 + c0i);
    br2 = *(const float2*)(bxr0 + w0 * 32 + c0i);
    bg2 = *(const float2*)(bxg0 + w0 * 32 + c0i);
    const float* hp = h0in + (size_t)(cl * 16 + bq) * 2 * kH + w0 * 32 + c0i;
    hm0r = hp[0]; hm1r = hp[1];
  } else {
    const int c0i = (tid & 7) * 2, bq = tid >> 3;
    bz2 = *(const float2*)(bxz1 + w1 * 16 + c0i);
    br2 = *(const float2*)(bxr1 + w1 * 16 + c0i);
    bg2 = *(const float2*)(bxg1 + w1 * 16 + c0i);
    if (bq < 16) {
      const float* hp = h0in + (size_t)(cl * 16 + bq) * 2 * kH + kH + w1 * 16 + c0i;
      hm0r = hp[0]; hm1r = hp[1];
    }
    if (w1 < 8) by_r = byv[w1 * 16 + (tid & 15)];
  }

  for (int tk = 0; tk < NT; ++tk) {
    const bool ev = (tk & 1) == 0;
    const int t = tk >> 1;          // L0 step (phase A at 2t, B at 2t+1)
    const int u = t - 1;            // L1 step
    const bool l0A = isL0 && ev && t < kS;
    const bool l0B = isL0 && !ev && t < kS;
    const bool l1A = !isL0 && ev && t >= 1 && t <= kS;
    const bool l1B = !isL0 && !ev && t >= 1 && t <= kS;
    const bool stH1 = !isL0 && ev && t >= 1 && t <= kS + 1;
    const bool yAct = !isL0 && ev && w1 < 8 && t >= 2 && t <= kS + 1;

    // ---- stage (coherent loads from IC) ----
    if (l0A) {
      stage_c(h0buf, pub0 + ((t - 1) & 1) * BPC * kH);
      int b = tid >> 4, i0 = (tid & 15) * 8;
      const float* xr = xg + ((size_t)(cl * 16 + b) * kS + t) * kI + i0;
      float4 v0 = *(const float4*)xr;
      float4 v1 = *(const float4*)(xr + 4);
      int4 pk;
      pk.x = (int)((u32)f2bf(v0.x) | ((u32)f2bf(v0.y) << 16));
      pk.y = (int)((u32)f2bf(v0.z) | ((u32)f2bf(v0.w) << 16));
      pk.z = (int)((u32)f2bf(v1.x) | ((u32)f2bf(v1.y) << 16));
      pk.w = (int)((u32)f2bf(v1.z) | ((u32)f2bf(v1.w) << 16));
      *(int4*)(xbuf + b * IP + i0) = pk;
    }
    if (!isL0 && ev) {  // L1 even: waves 0-1 stage h0, waves 2-3 stage h1 (parallel)
      if (tid < 128) {
        if (l1A) stage_c_half(h0buf, pub0 + (u & 1) * BPC * kH, tid);
      } else {
        if (stH1) stage_c_half(h1buf, pub1 + ((u - 1) & 1) * BPC * kH, tid - 128);
      }
    }
    if (l0B) stage_c(rhbuf, pr0 + (t & 1) * BPC * kH);
    if (l1B) stage_c(rhbuf, pr1 + (u & 1) * BPC * kH);
    __syncthreads();

    // ---- MFMA (A-frag: lane holds A[m=li][k=kh*256+s*32+q*8..+7]) ----
    if (l0A) {
      f32x4 hz = {0.f, 0.f, 0.f, 0.f}, hr = hz, xz = hz, xr2 = hz, xg2 = hz;
      const u16* ap = h0buf + li * HP + kh * 256 + q * 8;
#pragma unroll
      for (int s = 0; s < 8; ++s) {
        bf16x8 a = *(const bf16x8*)(ap + s * 32);
        hz = MFMA16(a, wA[0][s], hz);
        hr = MFMA16(a, wA[1][s], hr);
      }
      const u16* xp = xbuf + li * IP + kh * 64 + q * 8;
#pragma unroll
      for (int s = 0; s < 2; ++s) {
        bf16x8 a = *(const bf16x8*)(xp + s * 32);
        xz  = MFMA16(a, wE[0 + s], xz);
        xr2 = MFMA16(a, wE[2 + s], xr2);
        xg2 = MFMA16(a, wE[4 + s], xg2);
      }
      st_tile(spA + ((0 * 2 + nt) * 2 + kh) * 272, hz, q, li);
      st_tile(spA + ((1 * 2 + nt) * 2 + kh) * 272, hr, q, li);
      st_tile(spA + ((2 * 2 + nt) * 2 + kh) * 272, xz, q, li);
      st_tile(spA + ((3 * 2 + nt) * 2 + kh) * 272, xr2, q, li);
      st_tile(spA + ((4 * 2 + nt) * 2 + kh) * 272, xg2, q, li);
    } else if (!isL0 && ev) {
      if (xside) {
        if (l1A) {  // x-side of layer 1: input is h0(u)
          f32x4 cz = {0.f, 0.f, 0.f, 0.f}, cr = cz, cg = cz;
          const u16* ap = h0buf + li * HP + kh * 256 + q * 8;
#pragma unroll
          for (int s = 0; s < 8; ++s) {
            bf16x8 a = *(const bf16x8*)(ap + s * 32);
            cz = MFMA16(a, wA[0][s], cz);
            cr = MFMA16(a, wA[1][s], cr);
            cg = MFMA16(a, wA[2][s], cg);
          }
          st_tile(spA + (2 * 2 + kh) * 272, cz, q, li);
          st_tile(spA + (3 * 2 + kh) * 272, cr, q, li);
          st_tile(spA + (4 * 2 + kh) * 272, cg, q, li);
        }
      } else {
        const bool rec = t >= 1 && t <= kS;
        const bool ym = (w1 < 8) && t >= 2 && t <= kS + 1;
        if (rec || ym) {  // h-side z,r of layer 1 + y, both consume h1buf
          f32x4 cz = {0.f, 0.f, 0.f, 0.f}, cr = cz, cy = cz;
          const u16* ap = h1buf + li * HP + kh * 256 + q * 8;
#pragma unroll
          for (int s = 0; s < 8; ++s) {
            bf16x8 a = *(const bf16x8*)(ap + s * 32);
            if (rec) {
              cz = MFMA16(a, wA[0][s], cz);
              cr = MFMA16(a, wA[1][s], cr);
            }
            if (ym) cy = MFMA16(a, wE[s], cy);
          }
          if (rec) {
            st_tile(spA + (0 * 2 + kh) * 272, cz, q, li);
            st_tile(spA + (1 * 2 + kh) * 272, cr, q, li);
          }
          if (ym) st_tile(ypA + kh * 272, cy, q, li);
        }
      }
    } else if (l0B) {
      f32x4 cg = {0.f, 0.f, 0.f, 0.f};
      const u16* ap = rhbuf + li * HP + kh * 256 + q * 8;
#pragma unroll
      for (int s = 0; s < 8; ++s)
        cg = MFMA16(*(const bf16x8*)(ap + s * 32), wA[2][s], cg);
      st_tile(spB + (nt * 2 + kh) * 272, cg, q, li);
    } else if (l1B && !xside) {
      f32x4 cg = {0.f, 0.f, 0.f, 0.f};
      const u16* ap = rhbuf + li * HP + kh * 256 + q * 8;
#pragma unroll
      for (int s = 0; s < 8; ++s)
        cg = MFMA16(*(const bf16x8*)(ap + s * 32), wA[2][s], cg);
      st_tile(spB + kh * 272, cg, q, li);
    }
    __syncthreads();

    // ---- activations / publish (coherent stores to IC) ----
    if (l0A) {
      const int cp = tid & 15, b = tid >> 4;
      const int c0 = cp * 2, n2 = c0 >> 4, cc = c0 & 15, o = b * 17 + cc;
      float hz0 = spA[((0*2+n2)*2+0)*272 + o] + spA[((0*2+n2)*2+1)*272 + o];
      float hz1 = spA[((0*2+n2)*2+0)*272 + o+1] + spA[((0*2+n2)*2+1)*272 + o+1];
      float hr0 = spA[((1*2+n2)*2+0)*272 + o] + spA[((1*2+n2)*2+1)*272 + o];
      float hr1 = spA[((1*2+n2)*2+0)*272 + o+1] + spA[((1*2+n2)*2+1)*272 + o+1];
      float xz0 = spA[((2*2+n2)*2+0)*272 + o] + spA[((2*2+n2)*2+1)*272 + o];
      float xz1 = spA[((2*2+n2)*2+0)*272 + o+1] + spA[((2*2+n2)*2+1)*272 + o+1];
      float xr0 = spA[((3*2+n2)*2+0)*272 + o] + spA[((3*2+n2)*2+1)*272 + o];
      float xr1 = spA[((3*2+n2)*2+0)*272 + o+1] + spA[((3*2+n2)*2+1)*272 + o+1];
      float xg0 = spA[((4*2+n2)*2+0)*272 + o] + spA[((4*2+n2)*2+1)*272 + o];
      float xg1 = spA[((4*2+n2)*2+0)*272 + o+1] + spA[((4*2+n2)*2+1)*272 + o+1];
      zA0 = sigm(hz0 + xz0 + bz2.x);
      zA1 = sigm(hz1 + xz1 + bz2.y);
      float r0 = sigm(hr0 + xr0 + br2.x);
      float r1 = sigm(hr1 + xr1 + br2.y);
      gA0 = xg0 + bg2.x;
      gA1 = xg1 + bg2.y;
      pub2(pr0 + (t & 1) * BPC * kH, b * kH + w0 * 32 + c0, r0 * hm0r, r1 * hm1r);
    }
    if (l1A && tid < 128) {
      const int cp = tid & 7, b = tid >> 3;
      const int c0 = cp * 2, o = b * 17 + c0;
      float hz0 = spA[(0*2+0)*272 + o] + spA[(0*2+1)*272 + o];
      float hz1 = spA[(0*2+0)*272 + o+1] + spA[(0*2+1)*272 + o+1];
      float hr0 = spA[(1*2+0)*272 + o] + spA[(1*2+1)*272 + o];
      float hr1 = spA[(1*2+0)*272 + o+1] + spA[(1*2+1)*272 + o+1];
      float xz0 = spA[(2*2+0)*272 + o] + spA[(2*2+1)*272 + o];
      float xz1 = spA[(2*2+0)*272 + o+1] + spA[(2*2+1)*272 + o+1];
      float xr0 = spA[(3*2+0)*272 + o] + spA[(3*2+1)*272 + o];
      float xr1 = spA[(3*2+0)*272 + o+1] + spA[(3*2+1)*272 + o+1];
      float xg0 = spA[(4*2+0)*272 + o] + spA[(4*2+1)*272 + o];
      float xg1 = spA[(4*2+0)*272 + o+1] + spA[(4*2+1)*272 + o+1];
      zA0 = sigm(hz0 + xz0 + bz2.x);
      zA1 = sigm(hz1 + xz1 + bz2.y);
      float r0 = sigm(hr0 + xr0 + br2.x);
      float r1 = sigm(hr1 + xr1 + br2.y);
      gA0 = xg0 + bg2.x;
      gA1 = xg1 + bg2.y;
      pub2(pr1 + (u & 1) * BPC * kH, b * kH + w1 * 16 + c0, r0 * hm0r, r1 * hm1r);
    }
    if (yAct) {
      const int c = tid & 15, b = tid >> 4;
      float y = ypA[b * 17 + c] + ypA[272 + b * 17 + c] + by_r;
      out[((size_t)(cl * 16 + b) * kS + (t - 2)) * kO + w1 * 16 + c] = y;
    }
    if (l0B) {
      const int cp = tid & 15, b = tid >> 4;
      const int c0 = cp * 2, n2 = c0 >> 4, cc = c0 & 15, o = b * 17 + cc;
      float gh0 = spB[(n2*2+0)*272 + o] + spB[(n2*2+1)*272 + o];
      float gh1 = spB[(n2*2+0)*272 + o+1] + spB[(n2*2+1)*272 + o+1];
      float g0 = tanh_f(gA0 + gh0), g1 = tanh_f(gA1 + gh1);
      float hn0 = zA0 * hm0r + (1.f - zA0) * g0;
      float hn1 = zA1 * hm1r + (1.f - zA1) * g1;
      hm0r = hn0; hm1r = hn1;
      pub2(pub0 + (t & 1) * BPC * kH, b * kH + w0 * 32 + c0, hn0, hn1);
      if (t == kS - 1) {
        float* op = out + LOUT + (size_t)(cl * 16 + b) * 2 * kH + w0 * 32 + c0;
        op[0] = hn0; op[1] = hn1;
      }
    }
    if (l1B && tid < 128) {
      const int cp = tid & 7, b = tid >> 3;
      const int c0 = cp * 2, o = b * 17 + c0;
      float gh0 = spB[0 * 272 + o] + spB[1 * 272 + o];
      float gh1 = spB[0 * 272 + o+1] + spB[1 * 272 + o+1];
      float g0 = tanh_f(gA0 + gh0), g1 = tanh_f(gA1 + gh1);
      float hn0 = zA0 * hm0r + (1.f - zA0) * g0;
      float hn1 = zA1 * hm1r + (1.f - zA1) * g1;
      hm0r = hn0; hm1r = hn1;
      pub2(pub1 + (u & 1) * BPC * kH, b * kH + w1 * 16 + c0, hn0, hn1);
      if (u == kS - 1) {
        float* op = out + LOUT + (size_t)(cl * 16 + b) * 2 * kH + kH + w1 * 16 + c0;
        op[0] = hn0; op[1] = hn1;
      }
    }

    if (tk != NT - 1) cbar(flags, wid, (u32)(tk + 1));
  }
}

extern "C" void kernel_launch(void* const* d_in, const int* in_sizes, int n_in,
                              void* d_out, int out_size, void* d_ws, size_t ws_size,
                              hipStream_t stream) {
  (void)in_sizes; (void)n_in; (void)out_size; (void)ws_size;
  const float* x      = (const float*)d_in[0];
  const float* h0     = (const float*)d_in[1];
  const float* l0_wxz = (const float*)d_in[2];
  const float* l0_bxz = (const float*)d_in[3];
  const float* l0_whz = (const float*)d_in[4];
  const float* l0_wxr = (const float*)d_in[5];
  const float* l0_bxr = (const float*)d_in[6];
  const float* l0_whr = (const float*)d_in[7];
  const float* l0_wxg = (const float*)d_in[8];
  const float* l0_bxg = (const float*)d_in[9];
  const float* l0_whg = (const float*)d_in[10];
  const float* l1_wxz = (const float*)d_in[11];
  const float* l1_bxz = (const float*)d_in[12];
  const float* l1_whz = (const float*)d_in[13];
  const float* l1_wxr = (const float*)d_in[14];
  const float* l1_bxr = (const float*)d_in[15];
  const float* l1_whr = (const float*)d_in[16];
  const float* l1_wxg = (const float*)d_in[17];
  const float* l1_bxg = (const float*)d_in[18];
  const float* l1_whg = (const float*)d_in[19];
  const float* wy     = (const float*)d_in[20];
  const float* by     = (const float*)d_in[21];
  float* out = (float*)d_out;
  char* ws = (char*)d_ws;

  prep_kernel<<<512, 256, 0, stream>>>(l0_whz, l0_whr, l0_whg, l0_wxz, l0_wxr, l0_wxg,
                                       l1_wxz, l1_wxr, l1_wxg, l1_whz, l1_whr, l1_whg,
                                       wy, h0, ws);
  gru_kernel<<<NC * WGC, 256, 0, stream>>>(x, h0, l0_bxz, l0_bxr, l0_bxg,
                                           l1_bxz, l1_bxr, l1_bxg, by, out, ws);
}